// Round 6
// baseline (998.311 us; speedup 1.0000x reference)
//
#include <hip/hip_runtime.h>

typedef unsigned short u16;
typedef short short8 __attribute__((ext_vector_type(8)));
typedef float f32x4 __attribute__((ext_vector_type(4)));

// Static device scratch, 13 slots of MELEM u16 (218 MB total).
// slots 0-7: bf16 intermediates; 8-9: xn_f32; 10-11: x1_f32; 12: bf16 weights.
#define MELEM 8388608u  // 8192*1024
__device__ u16 g_ws[(size_t)MELEM * 13];

__device__ __forceinline__ float b2f(u16 u) {
  union { unsigned int i; float f; } v; v.i = ((unsigned int)u) << 16; return v.f;
}
__device__ __forceinline__ u16 f2b(float f) {
  union { float f; unsigned int i; } v; v.f = f;
  return (u16)((v.i + 0x7FFFu + ((v.i >> 16) & 1u)) >> 16);  // RNE
}
__device__ __forceinline__ f32x4 mfma16(short8 a, short8 b, f32x4 c) {
  return __builtin_amdgcn_mfma_f32_16x16x32_bf16(a, b, c, 0, 0, 0);
}

// ---- fp32 -> bf16 conversion (inputs are fp32; weights/A-operands need bf16)
__global__ __launch_bounds__(256) void convert_kernel(const float* __restrict__ src,
                                                      u16* __restrict__ dst, int n) {
  const int i = blockIdx.x * 256 + threadIdx.x;
  if (i < n) dst[i] = f2b(src[i]);
}

// ---------------- LayerNorm (torch: unbiased std, eps added to std)
// fp32 in, bf16 out (+ optional fp32 out for the residual stream)
__global__ __launch_bounds__(256) void ln_kernel(const float* __restrict__ x,
                                                 const float* __restrict__ alpha,
                                                 const float* __restrict__ beta,
                                                 u16* __restrict__ outb,
                                                 float* __restrict__ outf) {
  const int D = 1024;
  const int row = blockIdx.x;
  const int tid = threadIdx.x;
  const float4 u = *(const float4*)(x + (size_t)row * D + tid * 4);
  float s1 = u.x + u.y + u.z + u.w;
  float s2 = u.x * u.x + u.y * u.y + u.z * u.z + u.w * u.w;
#pragma unroll
  for (int off = 32; off >= 1; off >>= 1) {
    s1 += __shfl_xor(s1, off, 64);
    s2 += __shfl_xor(s2, off, 64);
  }
  __shared__ float ws1[4], ws2[4];
  if ((tid & 63) == 0) { ws1[tid >> 6] = s1; ws2[tid >> 6] = s2; }
  __syncthreads();
  s1 = ws1[0] + ws1[1] + ws1[2] + ws1[3];
  s2 = ws2[0] + ws2[1] + ws2[2] + ws2[3];
  const float mean = s1 * (1.0f / 1024.0f);
  const float var = fmaxf((s2 - 1024.0f * mean * mean) * (1.0f / 1023.0f), 0.0f);
  const float inv = 1.0f / (sqrtf(var) + 1e-6f);
  const float4 a = *(const float4*)(alpha + tid * 4);
  const float4 b = *(const float4*)(beta + tid * 4);
  const float o0 = a.x * (u.x - mean) * inv + b.x;
  const float o1 = a.y * (u.y - mean) * inv + b.y;
  const float o2 = a.z * (u.z - mean) * inv + b.z;
  const float o3 = a.w * (u.w - mean) * inv + b.w;
  ushort4 ob; ob.x = f2b(o0); ob.y = f2b(o1); ob.z = f2b(o2); ob.w = f2b(o3);
  *(ushort4*)(outb + (size_t)row * D + tid * 4) = ob;
  if (outf) {
    float4 of; of.x = o0; of.y = o1; of.z = o2; of.w = o3;
    *(float4*)(outf + (size_t)row * D + tid * 4) = of;
  }
}

// ---------------- MFMA GEMM: C = A(MxK,bf16) @ B(KxN,bf16) + bias_f32
// [+resid_f32] [+Cf accum]; relu; writes Cf (fp32) and/or Cb (bf16).
// 64x64 tile, 4 waves (2x2 of 32x32), BK=32, fp32 accum.
__global__ __launch_bounds__(256) void gemm_kernel(
    const u16* __restrict__ A, const u16* __restrict__ B,
    const float* __restrict__ bias, const float* __restrict__ resid,
    float* __restrict__ Cf, u16* __restrict__ Cb,
    int M, int N, int K, int relu, int accum) {
  __shared__ __align__(16) u16 As[64][40];
  __shared__ __align__(16) u16 Bt[64][40];
  const int tid = threadIdx.x;
  const int bn = blockIdx.x * 64;
  const int bm = blockIdx.y * 64;
  const int wv = tid >> 6, lane = tid & 63, quad = lane >> 4, l16 = lane & 15;
  const int wm = (wv >> 1) * 32, wn = (wv & 1) * 32;
  const int arow = tid >> 2, ac0 = (tid & 3) * 8;
  const int bkk = tid >> 3, bn0 = (tid & 7) * 8;
  f32x4 acc00 = {0.f, 0.f, 0.f, 0.f}, acc01 = {0.f, 0.f, 0.f, 0.f};
  f32x4 acc10 = {0.f, 0.f, 0.f, 0.f}, acc11 = {0.f, 0.f, 0.f, 0.f};
  for (int k0 = 0; k0 < K; k0 += 32) {
    int4 av = *(const int4*)(A + (size_t)(bm + arow) * K + k0 + ac0);
    int4 bv = *(const int4*)(B + (size_t)(k0 + bkk) * N + bn + bn0);
    *(int4*)&As[arow][ac0] = av;
    const u16* bs = (const u16*)&bv;
#pragma unroll
    for (int j = 0; j < 8; ++j) Bt[bn0 + j][bkk] = bs[j];
    __syncthreads();
    short8 a0 = *(const short8*)&As[wm + l16][quad * 8];
    short8 a1 = *(const short8*)&As[wm + 16 + l16][quad * 8];
    short8 b0 = *(const short8*)&Bt[wn + l16][quad * 8];
    short8 b1 = *(const short8*)&Bt[wn + 16 + l16][quad * 8];
    acc00 = mfma16(a0, b0, acc00);
    acc01 = mfma16(a0, b1, acc01);
    acc10 = mfma16(a1, b0, acc10);
    acc11 = mfma16(a1, b1, acc11);
    __syncthreads();
  }
#pragma unroll
  for (int mi = 0; mi < 2; ++mi) {
#pragma unroll
    for (int ni = 0; ni < 2; ++ni) {
      f32x4 a = (mi == 0) ? ((ni == 0) ? acc00 : acc01) : ((ni == 0) ? acc10 : acc11);
      const int col = bn + wn + ni * 16 + l16;
      const float bb = bias ? bias[col] : 0.0f;
#pragma unroll
      for (int r = 0; r < 4; ++r) {
        const int rowg = bm + wm + mi * 16 + quad * 4 + r;
        const size_t off = (size_t)rowg * N + col;
        float v = a[r] + bb;
        if (resid) v += resid[off];
        if (accum) v += Cf[off];
        if (relu) v = fmaxf(v, 0.0f);
        if (Cf) Cf[off] = v;
        if (Cb) Cb[off] = f2b(v);
      }
    }
  }
}

// ---------------- Flash attention (bf16 in/out), one block = (b,h,64 q rows)
__global__ __launch_bounds__(256) void attn_kernel(
    const u16* __restrict__ Q, const u16* __restrict__ Kb,
    const u16* __restrict__ Vb, u16* __restrict__ O) {
  const int S = 2048, D = 1024;
  __shared__ __align__(16) u16 Ks[64][72];
  __shared__ __align__(16) u16 Vt[64][72];
  __shared__ __align__(16) u16 Pb[4][16][72];
  const int tid = threadIdx.x;
  const int qt = blockIdx.x & 31;
  const int bh = blockIdx.x >> 5;
  const int b = bh >> 4, h = bh & 15;
  const int wv = tid >> 6, lane = tid & 63, quad = lane >> 4, l16 = lane & 15;
  const size_t base = ((size_t)b * S) * D + (size_t)h * 64;

  short8 qf[2];
  {
    const int qrow = qt * 64 + wv * 16 + l16;
#pragma unroll
    for (int ks = 0; ks < 2; ++ks) {
      int4 t = *(const int4*)(Q + base + (size_t)qrow * D + ks * 32 + quad * 8);
      const u16* p = (const u16*)&t;
      short8 f;
#pragma unroll
      for (int j = 0; j < 8; ++j) f[j] = (short)f2b(b2f(p[j]) * 0.125f);
      qf[ks] = f;
    }
  }

  float m_run[4], l_run[4];
  f32x4 acc[4];
  const f32x4 z4 = {0.f, 0.f, 0.f, 0.f};
#pragma unroll
  for (int r = 0; r < 4; ++r) { m_run[r] = -INFINITY; l_run[r] = 0.0f; }
#pragma unroll
  for (int ni = 0; ni < 4; ++ni) acc[ni] = z4;

  for (int kt = 0; kt < 32; ++kt) {
    const int kb = kt * 64;
#pragma unroll
    for (int it = 0; it < 2; ++it) {
      const int idx = it * 256 + tid;
      const int key = idx >> 3, c0 = (idx & 7) * 8;
      const size_t g = base + (size_t)(kb + key) * D + c0;
      int4 kv = *(const int4*)(Kb + g);
      *(int4*)&Ks[key][c0] = kv;
      int4 vv = *(const int4*)(Vb + g);
      const u16* vp = (const u16*)&vv;
#pragma unroll
      for (int j = 0; j < 8; ++j) Vt[c0 + j][key] = vp[j];
    }
    __syncthreads();

    f32x4 sc[4];
#pragma unroll
    for (int ni = 0; ni < 4; ++ni) {
      f32x4 s = z4;
#pragma unroll
      for (int ks = 0; ks < 2; ++ks) {
        short8 bf = *(const short8*)&Ks[ni * 16 + l16][ks * 32 + quad * 8];
        s = mfma16(qf[ks], bf, s);
      }
      sc[ni] = s;
    }

    float mx[4];
#pragma unroll
    for (int r = 0; r < 4; ++r)
      mx[r] = fmaxf(fmaxf(sc[0][r], sc[1][r]), fmaxf(sc[2][r], sc[3][r]));
#pragma unroll
    for (int off = 8; off >= 1; off >>= 1) {
#pragma unroll
      for (int r = 0; r < 4; ++r) mx[r] = fmaxf(mx[r], __shfl_xor(mx[r], off, 64));
    }
    float alpha[4];
#pragma unroll
    for (int r = 0; r < 4; ++r) {
      float nm = fmaxf(m_run[r], mx[r]);
      alpha[r] = __expf(m_run[r] - nm);
      m_run[r] = nm;
    }
#pragma unroll
    for (int ni = 0; ni < 4; ++ni) {
#pragma unroll
      for (int r = 0; r < 4; ++r) sc[ni][r] = __expf(sc[ni][r] - m_run[r]);
    }
    float ps[4];
#pragma unroll
    for (int r = 0; r < 4; ++r)
      ps[r] = (sc[0][r] + sc[1][r]) + (sc[2][r] + sc[3][r]);
#pragma unroll
    for (int off = 8; off >= 1; off >>= 1) {
#pragma unroll
      for (int r = 0; r < 4; ++r) ps[r] += __shfl_xor(ps[r], off, 64);
    }
#pragma unroll
    for (int r = 0; r < 4; ++r) l_run[r] = l_run[r] * alpha[r] + ps[r];
#pragma unroll
    for (int ni = 0; ni < 4; ++ni) {
#pragma unroll
      for (int r = 0; r < 4; ++r) acc[ni][r] *= alpha[r];
    }
#pragma unroll
    for (int ni = 0; ni < 4; ++ni) {
#pragma unroll
      for (int r = 0; r < 4; ++r)
        Pb[wv][quad * 4 + r][ni * 16 + l16] = f2b(sc[ni][r]);
    }
    __syncthreads();
#pragma unroll
    for (int ks = 0; ks < 2; ++ks) {
      short8 pf = *(const short8*)&Pb[wv][l16][ks * 32 + quad * 8];
#pragma unroll
      for (int ni = 0; ni < 4; ++ni) {
        short8 vf = *(const short8*)&Vt[ni * 16 + l16][ks * 32 + quad * 8];
        acc[ni] = mfma16(pf, vf, acc[ni]);
      }
    }
    __syncthreads();
  }

#pragma unroll
  for (int r = 0; r < 4; ++r) {
    const float rl = 1.0f / l_run[r];
    const int rowg = qt * 64 + wv * 16 + quad * 4 + r;
    const size_t ob = base + (size_t)rowg * D;
#pragma unroll
    for (int ni = 0; ni < 4; ++ni) O[ob + ni * 16 + l16] = f2b(acc[ni][r] * rl);
  }
}

extern "C" void kernel_launch(void* const* d_in, const int* in_sizes, int n_in,
                              void* d_out, int out_size, void* d_ws, size_t ws_size,
                              hipStream_t stream) {
  const int M = 8192, D = 1024, P = 256, DFF = 512;

  // fp32 inputs (established: reference is pure fp32)
  const float* feature_x = (const float*)d_in[0];
  const float* param_x   = (const float*)d_in[1];
  const float* Wq = (const float*)d_in[2];  const float* bq = (const float*)d_in[3];
  const float* Wk = (const float*)d_in[4];  const float* bk = (const float*)d_in[5];
  const float* Wv = (const float*)d_in[6];  const float* bv = (const float*)d_in[7];
  const float* Wo = (const float*)d_in[8];  const float* bo = (const float*)d_in[9];
  const float* alpha1 = (const float*)d_in[10]; const float* beta1 = (const float*)d_in[11];
  const float* alpha2 = (const float*)d_in[12]; const float* beta2 = (const float*)d_in[13];
  const float* W1 = (const float*)d_in[14]; const float* b1 = (const float*)d_in[15];
  const float* W2 = (const float*)d_in[16]; const float* b2 = (const float*)d_in[17];
  const float* Wp = (const float*)d_in[18]; const float* bp = (const float*)d_in[19];

  void* sym = nullptr;
  hipGetSymbolAddress(&sym, HIP_SYMBOL(g_ws));
  u16* s = (u16*)sym;

  // bf16 intermediates (slots 0-7)
  u16* xn_b   = s + (size_t)MELEM * 0;
  u16* qb     = s + (size_t)MELEM * 1;
  u16* kb     = s + (size_t)MELEM * 2;
  u16* vb     = s + (size_t)MELEM * 3;
  u16* ctx    = s + (size_t)MELEM * 4;
  u16* x2_b   = s + (size_t)MELEM * 5;
  u16* h1_b   = s + (size_t)MELEM * 6;     // 8192x512
  u16* xcp_b  = s + (size_t)MELEM * 7;     // bf16 copy of final x
  // fp32 residual stream (slots 8-11)
  float* xn_f = (float*)(s + (size_t)MELEM * 8);
  float* x1_f = (float*)(s + (size_t)MELEM * 10);
  // bf16 weights (slot 12)
  u16* wb = s + (size_t)MELEM * 12;
  u16* Wq_b = wb;                 u16* Wk_b = Wq_b + D * D;
  u16* Wv_b = Wk_b + D * D;       u16* Wo_b = Wv_b + D * D;
  u16* W1_b = Wo_b + D * D;       u16* W2_b = W1_b + D * DFF;
  u16* Wp_b = W2_b + DFF * D;     u16* px_b = Wp_b + (D + P) * P;

  float* xout_f = (float*)d_out;                  // x: 8192x1024 fp32
  float* pout_f = xout_f + (size_t)M * D;         // p: 8192x256 fp32

  dim3 blk(256);
  convert_kernel<<<(D * D + 255) / 256, blk, 0, stream>>>(Wq, Wq_b, D * D);
  convert_kernel<<<(D * D + 255) / 256, blk, 0, stream>>>(Wk, Wk_b, D * D);
  convert_kernel<<<(D * D + 255) / 256, blk, 0, stream>>>(Wv, Wv_b, D * D);
  convert_kernel<<<(D * D + 255) / 256, blk, 0, stream>>>(Wo, Wo_b, D * D);
  convert_kernel<<<(D * DFF + 255) / 256, blk, 0, stream>>>(W1, W1_b, D * DFF);
  convert_kernel<<<(DFF * D + 255) / 256, blk, 0, stream>>>(W2, W2_b, DFF * D);
  convert_kernel<<<((D + P) * P + 255) / 256, blk, 0, stream>>>(Wp, Wp_b, (D + P) * P);
  convert_kernel<<<(M * P + 255) / 256, blk, 0, stream>>>(param_x, px_b, M * P);

  // xn = LN1(feature_x)  [bf16 for GEMM A, fp32 for residual]
  ln_kernel<<<M, blk, 0, stream>>>(feature_x, alpha1, beta1, xn_b, xn_f);
  // q,k,v
  gemm_kernel<<<dim3(D / 64, M / 64), blk, 0, stream>>>(xn_b, Wq_b, bq, nullptr, nullptr, qb, M, D, D, 0, 0);
  gemm_kernel<<<dim3(D / 64, M / 64), blk, 0, stream>>>(xn_b, Wk_b, bk, nullptr, nullptr, kb, M, D, D, 0, 0);
  gemm_kernel<<<dim3(D / 64, M / 64), blk, 0, stream>>>(xn_b, Wv_b, bv, nullptr, nullptr, vb, M, D, D, 0, 0);
  // attention
  attn_kernel<<<2048, blk, 0, stream>>>(qb, kb, vb, ctx);
  // x1 = ctx@Wo + bo + xn   (fp32)
  gemm_kernel<<<dim3(D / 64, M / 64), blk, 0, stream>>>(ctx, Wo_b, bo, xn_f, x1_f, nullptr, M, D, D, 0, 0);
  // x2 = LN2(x1)  [bf16 only]
  ln_kernel<<<M, blk, 0, stream>>>(x1_f, alpha2, beta2, x2_b, nullptr);
  // h1 = relu(x2@W1 + b1)  [bf16]
  gemm_kernel<<<dim3(DFF / 64, M / 64), blk, 0, stream>>>(x2_b, W1_b, b1, nullptr, nullptr, h1_b, M, DFF, D, 1, 0);
  // x = h1@W2 + b2 + x1  -> fp32 d_out + bf16 copy for Wp GEMM
  gemm_kernel<<<dim3(D / 64, M / 64), blk, 0, stream>>>(h1_b, W2_b, b2, x1_f, xout_f, xcp_b, M, D, DFF, 0, 0);
  // p = x@Wp[:D] + bp  (fp32), then += param_x@Wp[D:]
  gemm_kernel<<<dim3(P / 64, M / 64), blk, 0, stream>>>(xcp_b, Wp_b, bp, nullptr, pout_f, nullptr, M, P, D, 0, 0);
  gemm_kernel<<<dim3(P / 64, M / 64), blk, 0, stream>>>(px_b, Wp_b + (size_t)D * P, nullptr, nullptr, pout_f, nullptr, M, P, P, 0, 1);
}

// Round 7
// 794.536 us; speedup vs baseline: 1.2565x; 1.2565x over previous
//
#include <hip/hip_runtime.h>

typedef unsigned short u16;
typedef short short8 __attribute__((ext_vector_type(8)));
typedef float f32x4 __attribute__((ext_vector_type(4)));

// Static device scratch: 13 x MELEM u16 slots.
#define MELEM 8388608u  // 8192*1024
__device__ u16 g_ws[(size_t)MELEM * 13];

__device__ __forceinline__ float b2f(u16 u) {
  union { unsigned int i; float f; } v; v.i = ((unsigned int)u) << 16; return v.f;
}
__device__ __forceinline__ u16 f2b(float f) {
  union { float f; unsigned int i; } v; v.f = f;
  return (u16)((v.i + 0x7FFFu + ((v.i >> 16) & 1u)) >> 16);  // RNE
}
__device__ __forceinline__ f32x4 mfma16(short8 a, short8 b, f32x4 c) {
  return __builtin_amdgcn_mfma_f32_16x16x32_bf16(a, b, c, 0, 0, 0);
}

typedef __attribute__((address_space(3))) unsigned int lds_u32;
typedef const __attribute__((address_space(1))) unsigned int glb_u32;
__device__ __forceinline__ void gld16(u16* l, const u16* g) {
  __builtin_amdgcn_global_load_lds((glb_u32*)g, (lds_u32*)l, 16, 0, 0);
}

// ---- fp32 -> bf16 elementwise
__global__ __launch_bounds__(256) void convert_kernel(const float* __restrict__ src,
                                                      u16* __restrict__ dst, int n) {
  const int i = blockIdx.x * 256 + threadIdx.x;
  if (i < n) dst[i] = f2b(src[i]);
}

// ---- fp32 W(KxN) -> bf16 Wt(NxK) tiled transpose
__global__ __launch_bounds__(256) void transpose_kernel(const float* __restrict__ W,
                                                        u16* __restrict__ Wt,
                                                        int K, int N) {
  __shared__ float tile[32][33];
  const int bx = blockIdx.x * 32;  // n
  const int by = blockIdx.y * 32;  // k
  const int tx = threadIdx.x & 31, ty = threadIdx.x >> 5;  // ty 0..7
#pragma unroll
  for (int i = 0; i < 32; i += 8)
    tile[ty + i][tx] = W[(size_t)(by + ty + i) * N + bx + tx];
  __syncthreads();
#pragma unroll
  for (int i = 0; i < 32; i += 8)
    Wt[(size_t)(bx + ty + i) * K + by + tx] = f2b(tile[tx][ty + i]);
}

// ---- concat 3x1024 fp32 biases
__global__ __launch_bounds__(256) void concat3_kernel(const float* __restrict__ a,
                                                      const float* __restrict__ b,
                                                      const float* __restrict__ c,
                                                      float* __restrict__ o) {
  const int i = blockIdx.x * 256 + threadIdx.x;
  if (i < 1024) o[i] = a[i];
  else if (i < 2048) o[i] = b[i - 1024];
  else if (i < 3072) o[i] = c[i - 2048];
}

// ---------------- LayerNorm (torch: unbiased std, eps on std); fp32 in, bf16(+fp32) out
__global__ __launch_bounds__(256) void ln_kernel(const float* __restrict__ x,
                                                 const float* __restrict__ alpha,
                                                 const float* __restrict__ beta,
                                                 u16* __restrict__ outb,
                                                 float* __restrict__ outf) {
  const int D = 1024;
  const int row = blockIdx.x;
  const int tid = threadIdx.x;
  const float4 u = *(const float4*)(x + (size_t)row * D + tid * 4);
  float s1 = u.x + u.y + u.z + u.w;
  float s2 = u.x * u.x + u.y * u.y + u.z * u.z + u.w * u.w;
#pragma unroll
  for (int off = 32; off >= 1; off >>= 1) {
    s1 += __shfl_xor(s1, off, 64);
    s2 += __shfl_xor(s2, off, 64);
  }
  __shared__ float ws1[4], ws2[4];
  if ((tid & 63) == 0) { ws1[tid >> 6] = s1; ws2[tid >> 6] = s2; }
  __syncthreads();
  s1 = ws1[0] + ws1[1] + ws1[2] + ws1[3];
  s2 = ws2[0] + ws2[1] + ws2[2] + ws2[3];
  const float mean = s1 * (1.0f / 1024.0f);
  const float var = fmaxf((s2 - 1024.0f * mean * mean) * (1.0f / 1023.0f), 0.0f);
  const float inv = 1.0f / (sqrtf(var) + 1e-6f);
  const float4 a = *(const float4*)(alpha + tid * 4);
  const float4 b = *(const float4*)(beta + tid * 4);
  const float o0 = a.x * (u.x - mean) * inv + b.x;
  const float o1 = a.y * (u.y - mean) * inv + b.y;
  const float o2 = a.z * (u.z - mean) * inv + b.z;
  const float o3 = a.w * (u.w - mean) * inv + b.w;
  ushort4 ob; ob.x = f2b(o0); ob.y = f2b(o1); ob.z = f2b(o2); ob.w = f2b(o3);
  *(ushort4*)(outb + (size_t)row * D + tid * 4) = ob;
  if (outf) {
    float4 of; of.x = o0; of.y = o1; of.z = o2; of.w = o3;
    *(float4*)(outf + (size_t)row * D + tid * 4) = of;
  }
}

// ---------------- m97-style MFMA GEMM: C = A(MxK) @ Bt(NxK)^T + bias [+resid] [relu]
// 128x128 tile, 4 waves (2x2 of 64x64), BK=32, global_load_lds width=16.
// Dual A-source: k < K1 from A (stride K1), else from A2 (stride K-K1).
__global__ __launch_bounds__(256) void gemm128(
    const u16* __restrict__ A, const u16* __restrict__ A2,
    const u16* __restrict__ Bt, const float* __restrict__ bias,
    const float* __restrict__ resid, float* __restrict__ Cf, u16* __restrict__ Cb,
    int M, int N, int K, int K1, int relu) {
  __shared__ __align__(16) u16 As[128 * 32];
  __shared__ __align__(16) u16 Bs[128 * 32];
  const int tid = threadIdx.x;
  const int bn = blockIdx.x * 128;
  const int bm = blockIdx.y * 128;
  const int wv = tid >> 6, lane = tid & 63, quad = lane >> 4, l16 = lane & 15;
  const int wm = (wv >> 1) * 64, wn = (wv & 1) * 64;
  const int r0 = tid >> 2;          // staging row 0..63
  const int cc = (tid & 3) * 8;     // staging col (u16)
  f32x4 acc[4][4];
#pragma unroll
  for (int i = 0; i < 4; ++i)
#pragma unroll
    for (int j = 0; j < 4; ++j) acc[i][j] = (f32x4){0.f, 0.f, 0.f, 0.f};

  for (int k0 = 0; k0 < K; k0 += 32) {
    const u16* aS; int lda, kk;
    if (A2 != nullptr && k0 >= K1) { aS = A2; lda = K - K1; kk = k0 - K1; }
    else { aS = A; lda = (A2 != nullptr) ? K1 : K; kk = k0; }
    gld16(&As[tid * 8],        aS + (size_t)(bm + r0) * lda + kk + cc);
    gld16(&As[2048 + tid * 8], aS + (size_t)(bm + 64 + r0) * lda + kk + cc);
    gld16(&Bs[tid * 8],        Bt + (size_t)(bn + r0) * K + k0 + cc);
    gld16(&Bs[2048 + tid * 8], Bt + (size_t)(bn + 64 + r0) * K + k0 + cc);
    __syncthreads();
    short8 af[4], bf[4];
#pragma unroll
    for (int mi = 0; mi < 4; ++mi)
      af[mi] = *(const short8*)&As[(wm + mi * 16 + l16) * 32 + quad * 8];
#pragma unroll
    for (int ni = 0; ni < 4; ++ni)
      bf[ni] = *(const short8*)&Bs[(wn + ni * 16 + l16) * 32 + quad * 8];
#pragma unroll
    for (int mi = 0; mi < 4; ++mi)
#pragma unroll
      for (int ni = 0; ni < 4; ++ni)
        acc[mi][ni] = mfma16(af[mi], bf[ni], acc[mi][ni]);
    __syncthreads();
  }

#pragma unroll
  for (int ni = 0; ni < 4; ++ni) {
    const int col = bn + wn + ni * 16 + l16;
    const float bb = bias ? bias[col] : 0.0f;
#pragma unroll
    for (int mi = 0; mi < 4; ++mi) {
#pragma unroll
      for (int r = 0; r < 4; ++r) {
        const int row = bm + wm + mi * 16 + quad * 4 + r;
        const size_t off = (size_t)row * N + col;
        float v = acc[mi][ni][r] + bb;
        if (resid) v += resid[off];
        if (relu) v = fmaxf(v, 0.0f);
        if (Cf) Cf[off] = v;
        if (Cb) Cb[off] = f2b(v);
      }
    }
  }
}

// ---------------- Flash attention; Q/K/V strided (ldq), O stride 1024.
__global__ __launch_bounds__(256) void attn_kernel(
    const u16* __restrict__ Q, const u16* __restrict__ Kb,
    const u16* __restrict__ Vb, u16* __restrict__ O, int ldq) {
  const int S = 2048;
  __shared__ __align__(16) u16 Ks[64][72];
  __shared__ __align__(16) u16 Vt[64][72];
  __shared__ __align__(16) u16 Pb[4][16][72];
  const int tid = threadIdx.x;
  const int qt = blockIdx.x & 31;
  const int bh = blockIdx.x >> 5;
  const int b = bh >> 4, h = bh & 15;
  const int wv = tid >> 6, lane = tid & 63, quad = lane >> 4, l16 = lane & 15;
  const size_t brow = (size_t)b * S;
  const size_t hoff = (size_t)h * 64;

  short8 qf[2];
  {
    const int qrow = qt * 64 + wv * 16 + l16;
#pragma unroll
    for (int ks = 0; ks < 2; ++ks) {
      int4 t = *(const int4*)(Q + (brow + qrow) * ldq + hoff + ks * 32 + quad * 8);
      const u16* p = (const u16*)&t;
      short8 f;
#pragma unroll
      for (int j = 0; j < 8; ++j) f[j] = (short)f2b(b2f(p[j]) * 0.125f);
      qf[ks] = f;
    }
  }

  float m_run[4], l_run[4];
  f32x4 acc[4];
  const f32x4 z4 = {0.f, 0.f, 0.f, 0.f};
#pragma unroll
  for (int r = 0; r < 4; ++r) { m_run[r] = -INFINITY; l_run[r] = 0.0f; }
#pragma unroll
  for (int ni = 0; ni < 4; ++ni) acc[ni] = z4;

  for (int kt = 0; kt < 32; ++kt) {
    const int kb = kt * 64;
#pragma unroll
    for (int it = 0; it < 2; ++it) {
      const int idx = it * 256 + tid;
      const int key = idx >> 3, c0 = (idx & 7) * 8;
      const size_t g = (brow + kb + key) * ldq + hoff + c0;
      int4 kv = *(const int4*)(Kb + g);
      *(int4*)&Ks[key][c0] = kv;
      int4 vv = *(const int4*)(Vb + g);
      const u16* vp = (const u16*)&vv;
      const int rot = idx & 7;  // bank-conflict-free rotation (8-way -> 2/bank)
#pragma unroll
      for (int j0 = 0; j0 < 8; ++j0) {
        const int j = (j0 + rot) & 7;
        Vt[c0 + j][key] = vp[j];
      }
    }
    __syncthreads();

    f32x4 sc[4];
#pragma unroll
    for (int ni = 0; ni < 4; ++ni) {
      f32x4 s = z4;
#pragma unroll
      for (int ks = 0; ks < 2; ++ks) {
        short8 bf = *(const short8*)&Ks[ni * 16 + l16][ks * 32 + quad * 8];
        s = mfma16(qf[ks], bf, s);
      }
      sc[ni] = s;
    }

    float mx[4];
#pragma unroll
    for (int r = 0; r < 4; ++r)
      mx[r] = fmaxf(fmaxf(sc[0][r], sc[1][r]), fmaxf(sc[2][r], sc[3][r]));
#pragma unroll
    for (int off = 8; off >= 1; off >>= 1) {
#pragma unroll
      for (int r = 0; r < 4; ++r) mx[r] = fmaxf(mx[r], __shfl_xor(mx[r], off, 64));
    }
    float alpha[4];
#pragma unroll
    for (int r = 0; r < 4; ++r) {
      float nm = fmaxf(m_run[r], mx[r]);
      alpha[r] = __expf(m_run[r] - nm);
      m_run[r] = nm;
    }
#pragma unroll
    for (int ni = 0; ni < 4; ++ni) {
#pragma unroll
      for (int r = 0; r < 4; ++r) sc[ni][r] = __expf(sc[ni][r] - m_run[r]);
    }
    float ps[4];
#pragma unroll
    for (int r = 0; r < 4; ++r)
      ps[r] = (sc[0][r] + sc[1][r]) + (sc[2][r] + sc[3][r]);
#pragma unroll
    for (int off = 8; off >= 1; off >>= 1) {
#pragma unroll
      for (int r = 0; r < 4; ++r) ps[r] += __shfl_xor(ps[r], off, 64);
    }
#pragma unroll
    for (int r = 0; r < 4; ++r) l_run[r] = l_run[r] * alpha[r] + ps[r];
#pragma unroll
    for (int ni = 0; ni < 4; ++ni) {
#pragma unroll
      for (int r = 0; r < 4; ++r) acc[ni][r] *= alpha[r];
    }
    // P: C-layout -> per-wave LDS slice -> A-layout (wave-internal, no barrier)
#pragma unroll
    for (int ni = 0; ni < 4; ++ni) {
#pragma unroll
      for (int r = 0; r < 4; ++r)
        Pb[wv][quad * 4 + r][ni * 16 + l16] = f2b(sc[ni][r]);
    }
#pragma unroll
    for (int ks = 0; ks < 2; ++ks) {
      short8 pf = *(const short8*)&Pb[wv][l16][ks * 32 + quad * 8];
#pragma unroll
      for (int ni = 0; ni < 4; ++ni) {
        short8 vf = *(const short8*)&Vt[ni * 16 + l16][ks * 32 + quad * 8];
        acc[ni] = mfma16(pf, vf, acc[ni]);
      }
    }
    __syncthreads();
  }

#pragma unroll
  for (int r = 0; r < 4; ++r) {
    const float rl = 1.0f / l_run[r];
    const int rowg = qt * 64 + wv * 16 + quad * 4 + r;
    const size_t ob = (brow + rowg) * 1024 + hoff;
#pragma unroll
    for (int ni = 0; ni < 4; ++ni) O[ob + ni * 16 + l16] = f2b(acc[ni][r] * rl);
  }
}

extern "C" void kernel_launch(void* const* d_in, const int* in_sizes, int n_in,
                              void* d_out, int out_size, void* d_ws, size_t ws_size,
                              hipStream_t stream) {
  const int M = 8192, D = 1024, P = 256, DFF = 512;

  const float* feature_x = (const float*)d_in[0];
  const float* param_x   = (const float*)d_in[1];
  const float* Wq = (const float*)d_in[2];  const float* bq = (const float*)d_in[3];
  const float* Wk = (const float*)d_in[4];  const float* bk = (const float*)d_in[5];
  const float* Wv = (const float*)d_in[6];  const float* bv = (const float*)d_in[7];
  const float* Wo = (const float*)d_in[8];  const float* bo = (const float*)d_in[9];
  const float* alpha1 = (const float*)d_in[10]; const float* beta1 = (const float*)d_in[11];
  const float* alpha2 = (const float*)d_in[12]; const float* beta2 = (const float*)d_in[13];
  const float* W1 = (const float*)d_in[14]; const float* b1 = (const float*)d_in[15];
  const float* W2 = (const float*)d_in[16]; const float* b2 = (const float*)d_in[17];
  const float* Wp = (const float*)d_in[18]; const float* bp = (const float*)d_in[19];

  void* sym = nullptr;
  hipGetSymbolAddress(&sym, HIP_SYMBOL(g_ws));
  u16* s = (u16*)sym;

  u16* xn_b   = s + (size_t)MELEM * 0;
  float* xn_f = (float*)(s + (size_t)MELEM * 1);   // slots 1-2
  u16* qkv_b  = s + (size_t)MELEM * 3;             // slots 3-5 (M x 3072)
  u16* ctx    = s + (size_t)MELEM * 6;
  float* x1_f = (float*)(s + (size_t)MELEM * 7);   // slots 7-8
  u16* x2_b   = s + (size_t)MELEM * 9;
  u16* h1_b   = s + (size_t)MELEM * 10;            // M x 512
  u16* xcp_b  = s + (size_t)MELEM * 11;
  u16* wreg   = s + (size_t)MELEM * 12;
  u16* px_b   = wreg;                              // M x 256       = 2,097,152
  u16* Wqkvt  = px_b + 2097152;                    // 3072 x 1024   = 3,145,728
  u16* Wot    = Wqkvt + 3145728;                   // 1024 x 1024
  u16* W1t    = Wot + 1048576;                     // 512 x 1024
  u16* W2t    = W1t + 524288;                      // 1024 x 512
  u16* Wpt    = W2t + 524288;                      // 256 x 1280
  float* bqkv = (float*)(Wpt + 327680);            // 3072 fp32

  float* xout_f = (float*)d_out;
  float* pout_f = xout_f + (size_t)M * D;

  dim3 blk(256);
  // weight prep
  transpose_kernel<<<dim3(32, 32), blk, 0, stream>>>(Wq, Wqkvt, D, D);
  transpose_kernel<<<dim3(32, 32), blk, 0, stream>>>(Wk, Wqkvt + 1024 * 1024, D, D);
  transpose_kernel<<<dim3(32, 32), blk, 0, stream>>>(Wv, Wqkvt + 2048 * 1024, D, D);
  transpose_kernel<<<dim3(32, 32), blk, 0, stream>>>(Wo, Wot, D, D);
  transpose_kernel<<<dim3(16, 32), blk, 0, stream>>>(W1, W1t, D, DFF);
  transpose_kernel<<<dim3(32, 16), blk, 0, stream>>>(W2, W2t, DFF, D);
  transpose_kernel<<<dim3(8, 40), blk, 0, stream>>>(Wp, Wpt, D + P, P);
  concat3_kernel<<<12, blk, 0, stream>>>(bq, bk, bv, bqkv);
  convert_kernel<<<(M * P + 255) / 256, blk, 0, stream>>>(param_x, px_b, M * P);

  // pipeline
  ln_kernel<<<M, blk, 0, stream>>>(feature_x, alpha1, beta1, xn_b, xn_f);
  gemm128<<<dim3(24, 64), blk, 0, stream>>>(xn_b, nullptr, Wqkvt, bqkv, nullptr,
                                            nullptr, qkv_b, M, 3072, D, D, 0);
  attn_kernel<<<2048, blk, 0, stream>>>(qkv_b, qkv_b + 1024, qkv_b + 2048, ctx, 3072);
  gemm128<<<dim3(8, 64), blk, 0, stream>>>(ctx, nullptr, Wot, bo, xn_f,
                                           x1_f, nullptr, M, D, D, D, 0);
  ln_kernel<<<M, blk, 0, stream>>>(x1_f, alpha2, beta2, x2_b, nullptr);
  gemm128<<<dim3(4, 64), blk, 0, stream>>>(x2_b, nullptr, W1t, b1, nullptr,
                                           nullptr, h1_b, M, DFF, D, D, 1);
  gemm128<<<dim3(8, 64), blk, 0, stream>>>(h1_b, nullptr, W2t, b2, x1_f,
                                           xout_f, xcp_b, M, D, DFF, DFF, 0);
  gemm128<<<dim3(2, 64), blk, 0, stream>>>(xcp_b, px_b, Wpt, bp, nullptr,
                                           pout_f, nullptr, M, P, D + P, D, 0);
}

// Round 8
// 678.346 us; speedup vs baseline: 1.4717x; 1.1713x over previous
//
#include <hip/hip_runtime.h>

typedef unsigned short u16;
typedef short short8 __attribute__((ext_vector_type(8)));
typedef float f32x4 __attribute__((ext_vector_type(4)));

// Static device scratch: 13 x MELEM u16 slots.
#define MELEM 8388608u  // 8192*1024
__device__ u16 g_ws[(size_t)MELEM * 13];

__device__ __forceinline__ float b2f(u16 u) {
  union { unsigned int i; float f; } v; v.i = ((unsigned int)u) << 16; return v.f;
}
__device__ __forceinline__ u16 f2b(float f) {
  union { float f; unsigned int i; } v; v.f = f;
  return (u16)((v.i + 0x7FFFu + ((v.i >> 16) & 1u)) >> 16);  // RNE
}
__device__ __forceinline__ f32x4 mfma16(short8 a, short8 b, f32x4 c) {
  return __builtin_amdgcn_mfma_f32_16x16x32_bf16(a, b, c, 0, 0, 0);
}

typedef __attribute__((address_space(3))) unsigned int lds_u32;
typedef const __attribute__((address_space(1))) unsigned int glb_u32;
__device__ __forceinline__ void gld16(u16* l, const u16* g) {
  __builtin_amdgcn_global_load_lds((glb_u32*)g, (lds_u32*)l, 16, 0, 0);
}

// ---- fp32 -> bf16 elementwise
__global__ __launch_bounds__(256) void convert_kernel(const float* __restrict__ src,
                                                      u16* __restrict__ dst, int n) {
  const int i = blockIdx.x * 256 + threadIdx.x;
  if (i < n) dst[i] = f2b(src[i]);
}

// ---- fp32 W(KxN) -> bf16 Wt(NxK) tiled transpose
__global__ __launch_bounds__(256) void transpose_kernel(const float* __restrict__ W,
                                                        u16* __restrict__ Wt,
                                                        int K, int N) {
  __shared__ float tile[32][33];
  const int bx = blockIdx.x * 32;  // n
  const int by = blockIdx.y * 32;  // k
  const int tx = threadIdx.x & 31, ty = threadIdx.x >> 5;  // ty 0..7
#pragma unroll
  for (int i = 0; i < 32; i += 8)
    tile[ty + i][tx] = W[(size_t)(by + ty + i) * N + bx + tx];
  __syncthreads();
#pragma unroll
  for (int i = 0; i < 32; i += 8)
    Wt[(size_t)(bx + ty + i) * K + by + tx] = f2b(tile[tx][ty + i]);
}

// ---- concat 3x1024 fp32 biases
__global__ __launch_bounds__(256) void concat3_kernel(const float* __restrict__ a,
                                                      const float* __restrict__ b,
                                                      const float* __restrict__ c,
                                                      float* __restrict__ o) {
  const int i = blockIdx.x * 256 + threadIdx.x;
  if (i < 1024) o[i] = a[i];
  else if (i < 2048) o[i] = b[i - 1024];
  else if (i < 3072) o[i] = c[i - 2048];
}

// ---------------- LayerNorm (torch: unbiased std, eps on std); fp32 in, bf16(+fp32) out
__global__ __launch_bounds__(256) void ln_kernel(const float* __restrict__ x,
                                                 const float* __restrict__ alpha,
                                                 const float* __restrict__ beta,
                                                 u16* __restrict__ outb,
                                                 float* __restrict__ outf) {
  const int D = 1024;
  const int row = blockIdx.x;
  const int tid = threadIdx.x;
  const float4 u = *(const float4*)(x + (size_t)row * D + tid * 4);
  float s1 = u.x + u.y + u.z + u.w;
  float s2 = u.x * u.x + u.y * u.y + u.z * u.z + u.w * u.w;
#pragma unroll
  for (int off = 32; off >= 1; off >>= 1) {
    s1 += __shfl_xor(s1, off, 64);
    s2 += __shfl_xor(s2, off, 64);
  }
  __shared__ float ws1[4], ws2[4];
  if ((tid & 63) == 0) { ws1[tid >> 6] = s1; ws2[tid >> 6] = s2; }
  __syncthreads();
  s1 = ws1[0] + ws1[1] + ws1[2] + ws1[3];
  s2 = ws2[0] + ws2[1] + ws2[2] + ws2[3];
  const float mean = s1 * (1.0f / 1024.0f);
  const float var = fmaxf((s2 - 1024.0f * mean * mean) * (1.0f / 1023.0f), 0.0f);
  const float inv = 1.0f / (sqrtf(var) + 1e-6f);
  const float4 a = *(const float4*)(alpha + tid * 4);
  const float4 b = *(const float4*)(beta + tid * 4);
  const float o0 = a.x * (u.x - mean) * inv + b.x;
  const float o1 = a.y * (u.y - mean) * inv + b.y;
  const float o2 = a.z * (u.z - mean) * inv + b.z;
  const float o3 = a.w * (u.w - mean) * inv + b.w;
  ushort4 ob; ob.x = f2b(o0); ob.y = f2b(o1); ob.z = f2b(o2); ob.w = f2b(o3);
  *(ushort4*)(outb + (size_t)row * D + tid * 4) = ob;
  if (outf) {
    float4 of; of.x = o0; of.y = o1; of.z = o2; of.w = o3;
    *(float4*)(outf + (size_t)row * D + tid * 4) = of;
  }
}

// ---------------- m97-style MFMA GEMM: C = A(MxK) @ Bt(NxK)^T + bias [+resid] [relu]
// 128x128 tile, 4 waves (2x2 of 64x64), BK=32, global_load_lds width=16.
__global__ __launch_bounds__(256) void gemm128(
    const u16* __restrict__ A, const u16* __restrict__ A2,
    const u16* __restrict__ Bt, const float* __restrict__ bias,
    const float* __restrict__ resid, float* __restrict__ Cf, u16* __restrict__ Cb,
    int M, int N, int K, int K1, int relu) {
  __shared__ __align__(16) u16 As[128 * 32];
  __shared__ __align__(16) u16 Bs[128 * 32];
  const int tid = threadIdx.x;
  const int bn = blockIdx.x * 128;
  const int bm = blockIdx.y * 128;
  const int wv = tid >> 6, lane = tid & 63, quad = lane >> 4, l16 = lane & 15;
  const int wm = (wv >> 1) * 64, wn = (wv & 1) * 64;
  const int r0 = tid >> 2;
  const int cc = (tid & 3) * 8;
  f32x4 acc[4][4];
#pragma unroll
  for (int i = 0; i < 4; ++i)
#pragma unroll
    for (int j = 0; j < 4; ++j) acc[i][j] = (f32x4){0.f, 0.f, 0.f, 0.f};

  for (int k0 = 0; k0 < K; k0 += 32) {
    const u16* aS; int lda, kk;
    if (A2 != nullptr && k0 >= K1) { aS = A2; lda = K - K1; kk = k0 - K1; }
    else { aS = A; lda = (A2 != nullptr) ? K1 : K; kk = k0; }
    gld16(&As[tid * 8],        aS + (size_t)(bm + r0) * lda + kk + cc);
    gld16(&As[2048 + tid * 8], aS + (size_t)(bm + 64 + r0) * lda + kk + cc);
    gld16(&Bs[tid * 8],        Bt + (size_t)(bn + r0) * K + k0 + cc);
    gld16(&Bs[2048 + tid * 8], Bt + (size_t)(bn + 64 + r0) * K + k0 + cc);
    __syncthreads();
    short8 af[4], bf[4];
#pragma unroll
    for (int mi = 0; mi < 4; ++mi)
      af[mi] = *(const short8*)&As[(wm + mi * 16 + l16) * 32 + quad * 8];
#pragma unroll
    for (int ni = 0; ni < 4; ++ni)
      bf[ni] = *(const short8*)&Bs[(wn + ni * 16 + l16) * 32 + quad * 8];
#pragma unroll
    for (int mi = 0; mi < 4; ++mi)
#pragma unroll
      for (int ni = 0; ni < 4; ++ni)
        acc[mi][ni] = mfma16(af[mi], bf[ni], acc[mi][ni]);
    __syncthreads();
  }

#pragma unroll
  for (int ni = 0; ni < 4; ++ni) {
    const int col = bn + wn + ni * 16 + l16;
    const float bb = bias ? bias[col] : 0.0f;
#pragma unroll
    for (int mi = 0; mi < 4; ++mi) {
#pragma unroll
      for (int r = 0; r < 4; ++r) {
        const int row = bm + wm + mi * 16 + quad * 4 + r;
        const size_t off = (size_t)row * N + col;
        float v = acc[mi][ni][r] + bb;
        if (resid) v += resid[off];
        if (relu) v = fmaxf(v, 0.0f);
        if (Cf) Cf[off] = v;
        if (Cb) Cb[off] = f2b(v);
      }
    }
  }
}

// ---------------- Flash attention, transposed orientation.
// S^T = K@Q^T (A=K-frag, B=Q-frag), O^T = V^T@P^T (A=Vt-frag, B=P-frag).
// Fixed-reference softmax (no running max; scores clamped at 60 — data-safe).
// Block = (b, h, 128 q rows); wave = 32 q rows; K-tiles of 128 keys.
__global__ __launch_bounds__(256) void attn_kernel(
    const u16* __restrict__ Q, const u16* __restrict__ Kb,
    const u16* __restrict__ Vb, u16* __restrict__ O, int ldq) {
  const int S = 2048;
  __shared__ __align__(16) u16 Ks[128][72];     // [key][dh]
  __shared__ __align__(16) u16 Vt[64][136];     // [dh][key] (transposed)
  __shared__ __align__(16) u16 Pb[4][32][40];   // per-wave P^T quarter: [qrow][key32]
  const int tid = threadIdx.x;
  const int qt = blockIdx.x & 15;
  const int bh = blockIdx.x >> 4;
  const int b = bh >> 4, h = bh & 15;
  const int wv = tid >> 6, lane = tid & 63, quad = lane >> 4, l16 = lane & 15;
  const size_t brow = (size_t)b * S;
  const size_t hoff = (size_t)h * 64;
  const int q0 = qt * 128 + wv * 32;

  // Q B-frags [ni][ks] (n=qrow=l16+16ni, k=dh=ks*32+quad*8+j), scaled by 0.125
  short8 qf[2][2];
#pragma unroll
  for (int ni = 0; ni < 2; ++ni)
#pragma unroll
    for (int ks = 0; ks < 2; ++ks) {
      int4 t = *(const int4*)(Q + (brow + q0 + ni * 16 + l16) * ldq + hoff + ks * 32 + quad * 8);
      const u16* p = (const u16*)&t;
      short8 f;
#pragma unroll
      for (int j = 0; j < 8; ++j) f[j] = (short)f2b(b2f(p[j]) * 0.125f);
      qf[ni][ks] = f;
    }

  f32x4 oacc[4][2];
#pragma unroll
  for (int mi = 0; mi < 4; ++mi)
#pragma unroll
    for (int ni = 0; ni < 2; ++ni) oacc[mi][ni] = (f32x4){0.f, 0.f, 0.f, 0.f};
  float lsum[2] = {0.0f, 0.0f};
  const f32x4 z4 = {0.f, 0.f, 0.f, 0.f};

  for (int kt = 0; kt < 16; ++kt) {
    const int kb = kt * 128;
#pragma unroll
    for (int it = 0; it < 4; ++it) {
      const int idx = it * 256 + tid;
      const int key = idx >> 3, c0 = (idx & 7) * 8;
      const size_t g = (brow + kb + key) * ldq + hoff + c0;
      int4 kv = *(const int4*)(Kb + g);
      *(int4*)&Ks[key][c0] = kv;
      int4 vv = *(const int4*)(Vb + g);
      const u16* vp = (const u16*)&vv;
      const int rot = idx & 7;
#pragma unroll
      for (int j0 = 0; j0 < 8; ++j0) {
        const int j = (j0 + rot) & 7;
        Vt[c0 + j][key] = vp[j];
      }
    }
    __syncthreads();

#pragma unroll
    for (int kk = 0; kk < 4; ++kk) {
      // S^T for 32 keys (two 16-key sub-tiles), exp, pack into Pb quarter
#pragma unroll
      for (int half = 0; half < 2; ++half) {
        const int mi = kk * 2 + half;
        short8 af0 = *(const short8*)&Ks[mi * 16 + l16][quad * 8];
        short8 af1 = *(const short8*)&Ks[mi * 16 + l16][32 + quad * 8];
#pragma unroll
        for (int ni = 0; ni < 2; ++ni) {
          f32x4 s = z4;
          s = mfma16(af0, qf[ni][0], s);
          s = mfma16(af1, qf[ni][1], s);
          const float e0 = __expf(fminf(s[0], 60.0f));
          const float e1 = __expf(fminf(s[1], 60.0f));
          const float e2 = __expf(fminf(s[2], 60.0f));
          const float e3 = __expf(fminf(s[3], 60.0f));
          lsum[ni] += (e0 + e1) + (e2 + e3);
          uint2 pk;
          pk.x = ((unsigned int)f2b(e1) << 16) | f2b(e0);
          pk.y = ((unsigned int)f2b(e3) << 16) | f2b(e2);
          *(uint2*)&Pb[wv][ni * 16 + l16][half * 16 + quad * 4] = pk;
        }
      }
      // PV for this 32-key quarter
      short8 pf[2];
#pragma unroll
      for (int ni = 0; ni < 2; ++ni)
        pf[ni] = *(const short8*)&Pb[wv][ni * 16 + l16][quad * 8];
#pragma unroll
      for (int mi2 = 0; mi2 < 4; ++mi2) {
        short8 vf = *(const short8*)&Vt[mi2 * 16 + l16][kk * 32 + quad * 8];
#pragma unroll
        for (int ni = 0; ni < 2; ++ni)
          oacc[mi2][ni] = mfma16(vf, pf[ni], oacc[mi2][ni]);
      }
    }
    __syncthreads();
  }

#pragma unroll
  for (int ni = 0; ni < 2; ++ni) {
    lsum[ni] += __shfl_xor(lsum[ni], 16, 64);
    lsum[ni] += __shfl_xor(lsum[ni], 32, 64);
  }
  const float rl0 = 1.0f / lsum[0], rl1 = 1.0f / lsum[1];
#pragma unroll
  for (int ni = 0; ni < 2; ++ni) {
    const float rl = (ni == 0) ? rl0 : rl1;
    const size_t ob = (brow + q0 + ni * 16 + l16) * 1024 + hoff;
#pragma unroll
    for (int mi2 = 0; mi2 < 4; ++mi2) {
      ushort4 ov;
      ov.x = f2b(oacc[mi2][ni][0] * rl);
      ov.y = f2b(oacc[mi2][ni][1] * rl);
      ov.z = f2b(oacc[mi2][ni][2] * rl);
      ov.w = f2b(oacc[mi2][ni][3] * rl);
      *(ushort4*)(O + ob + mi2 * 16 + quad * 4) = ov;
    }
  }
}

extern "C" void kernel_launch(void* const* d_in, const int* in_sizes, int n_in,
                              void* d_out, int out_size, void* d_ws, size_t ws_size,
                              hipStream_t stream) {
  const int M = 8192, D = 1024, P = 256, DFF = 512;

  const float* feature_x = (const float*)d_in[0];
  const float* param_x   = (const float*)d_in[1];
  const float* Wq = (const float*)d_in[2];  const float* bq = (const float*)d_in[3];
  const float* Wk = (const float*)d_in[4];  const float* bk = (const float*)d_in[5];
  const float* Wv = (const float*)d_in[6];  const float* bv = (const float*)d_in[7];
  const float* Wo = (const float*)d_in[8];  const float* bo = (const float*)d_in[9];
  const float* alpha1 = (const float*)d_in[10]; const float* beta1 = (const float*)d_in[11];
  const float* alpha2 = (const float*)d_in[12]; const float* beta2 = (const float*)d_in[13];
  const float* W1 = (const float*)d_in[14]; const float* b1 = (const float*)d_in[15];
  const float* W2 = (const float*)d_in[16]; const float* b2 = (const float*)d_in[17];
  const float* Wp = (const float*)d_in[18]; const float* bp = (const float*)d_in[19];

  void* sym = nullptr;
  hipGetSymbolAddress(&sym, HIP_SYMBOL(g_ws));
  u16* s = (u16*)sym;

  u16* xn_b   = s + (size_t)MELEM * 0;
  float* xn_f = (float*)(s + (size_t)MELEM * 1);   // slots 1-2
  u16* qkv_b  = s + (size_t)MELEM * 3;             // slots 3-5 (M x 3072)
  u16* ctx    = s + (size_t)MELEM * 6;
  float* x1_f = (float*)(s + (size_t)MELEM * 7);   // slots 7-8
  u16* x2_b   = s + (size_t)MELEM * 9;
  u16* h1_b   = s + (size_t)MELEM * 10;            // M x 512
  u16* xcp_b  = s + (size_t)MELEM * 11;
  u16* wreg   = s + (size_t)MELEM * 12;
  u16* px_b   = wreg;                              // M x 256
  u16* Wqkvt  = px_b + 2097152;                    // 3072 x 1024
  u16* Wot    = Wqkvt + 3145728;                   // 1024 x 1024
  u16* W1t    = Wot + 1048576;                     // 512 x 1024
  u16* W2t    = W1t + 524288;                      // 1024 x 512
  u16* Wpt    = W2t + 524288;                      // 256 x 1280
  float* bqkv = (float*)(Wpt + 327680);            // 3072 fp32

  float* xout_f = (float*)d_out;
  float* pout_f = xout_f + (size_t)M * D;

  dim3 blk(256);
  // weight prep
  transpose_kernel<<<dim3(32, 32), blk, 0, stream>>>(Wq, Wqkvt, D, D);
  transpose_kernel<<<dim3(32, 32), blk, 0, stream>>>(Wk, Wqkvt + 1024 * 1024, D, D);
  transpose_kernel<<<dim3(32, 32), blk, 0, stream>>>(Wv, Wqkvt + 2048 * 1024, D, D);
  transpose_kernel<<<dim3(32, 32), blk, 0, stream>>>(Wo, Wot, D, D);
  transpose_kernel<<<dim3(16, 32), blk, 0, stream>>>(W1, W1t, D, DFF);
  transpose_kernel<<<dim3(32, 16), blk, 0, stream>>>(W2, W2t, DFF, D);
  transpose_kernel<<<dim3(8, 40), blk, 0, stream>>>(Wp, Wpt, D + P, P);
  concat3_kernel<<<12, blk, 0, stream>>>(bq, bk, bv, bqkv);
  convert_kernel<<<(M * P + 255) / 256, blk, 0, stream>>>(param_x, px_b, M * P);

  // pipeline
  ln_kernel<<<M, blk, 0, stream>>>(feature_x, alpha1, beta1, xn_b, xn_f);
  gemm128<<<dim3(24, 64), blk, 0, stream>>>(xn_b, nullptr, Wqkvt, bqkv, nullptr,
                                            nullptr, qkv_b, M, 3072, D, D, 0);
  attn_kernel<<<1024, blk, 0, stream>>>(qkv_b, qkv_b + 1024, qkv_b + 2048, ctx, 3072);
  gemm128<<<dim3(8, 64), blk, 0, stream>>>(ctx, nullptr, Wot, bo, xn_f,
                                           x1_f, nullptr, M, D, D, D, 0);
  ln_kernel<<<M, blk, 0, stream>>>(x1_f, alpha2, beta2, x2_b, nullptr);
  gemm128<<<dim3(4, 64), blk, 0, stream>>>(x2_b, nullptr, W1t, b1, nullptr,
                                           nullptr, h1_b, M, DFF, D, D, 1);
  gemm128<<<dim3(8, 64), blk, 0, stream>>>(h1_b, nullptr, W2t, b2, x1_f,
                                           xout_f, xcp_b, M, D, DFF, DFF, 0);
  gemm128<<<dim3(2, 64), blk, 0, stream>>>(xcp_b, px_b, Wpt, bp, nullptr,
                                           pout_f, nullptr, M, P, D + P, D, 0);
}

// Round 9
// 659.074 us; speedup vs baseline: 1.5147x; 1.0292x over previous
//
#include <hip/hip_runtime.h>
#include <hip/hip_bf16.h>

typedef unsigned short u16;
typedef short short8 __attribute__((ext_vector_type(8)));
typedef float f32x4 __attribute__((ext_vector_type(4)));

// Static device scratch: 13 x MELEM u16 slots.
#define MELEM 8388608u  // 8192*1024
__device__ u16 g_ws[(size_t)MELEM * 13];

__device__ __forceinline__ float b2f(u16 u) {
  union { unsigned int i; float f; } v; v.i = ((unsigned int)u) << 16; return v.f;
}
__device__ __forceinline__ u16 f2b(float f) {
  union { float f; unsigned int i; } v; v.f = f;
  return (u16)((v.i + 0x7FFFu + ((v.i >> 16) & 1u)) >> 16);  // RNE
}
__device__ __forceinline__ unsigned int pk2(float a, float b) {
  union { __hip_bfloat162 h; unsigned int u; } v;
  v.h = __float22bfloat162_rn(make_float2(a, b));  // v_cvt_pk_bf16_f32 (RNE)
  return v.u;
}
__device__ __forceinline__ f32x4 mfma16(short8 a, short8 b, f32x4 c) {
  return __builtin_amdgcn_mfma_f32_16x16x32_bf16(a, b, c, 0, 0, 0);
}

typedef __attribute__((address_space(3))) unsigned int lds_u32;
typedef const __attribute__((address_space(1))) unsigned int glb_u32;
__device__ __forceinline__ void gld16(u16* l, const u16* g) {
  __builtin_amdgcn_global_load_lds((glb_u32*)g, (lds_u32*)l, 16, 0, 0);
}

// ---- fp32 -> bf16 elementwise
__global__ __launch_bounds__(256) void convert_kernel(const float* __restrict__ src,
                                                      u16* __restrict__ dst, int n) {
  const int i = blockIdx.x * 256 + threadIdx.x;
  if (i < n) dst[i] = f2b(src[i]);
}

// ---- fp32 W(KxN) -> bf16 Wt(NxK) tiled transpose
__global__ __launch_bounds__(256) void transpose_kernel(const float* __restrict__ W,
                                                        u16* __restrict__ Wt,
                                                        int K, int N) {
  __shared__ float tile[32][33];
  const int bx = blockIdx.x * 32;
  const int by = blockIdx.y * 32;
  const int tx = threadIdx.x & 31, ty = threadIdx.x >> 5;
#pragma unroll
  for (int i = 0; i < 32; i += 8)
    tile[ty + i][tx] = W[(size_t)(by + ty + i) * N + bx + tx];
  __syncthreads();
#pragma unroll
  for (int i = 0; i < 32; i += 8)
    Wt[(size_t)(bx + ty + i) * K + by + tx] = f2b(tile[tx][ty + i]);
}

// ---- concat 3x1024 fp32 biases
__global__ __launch_bounds__(256) void concat3_kernel(const float* __restrict__ a,
                                                      const float* __restrict__ b,
                                                      const float* __restrict__ c,
                                                      float* __restrict__ o) {
  const int i = blockIdx.x * 256 + threadIdx.x;
  if (i < 1024) o[i] = a[i];
  else if (i < 2048) o[i] = b[i - 1024];
  else if (i < 3072) o[i] = c[i - 2048];
}

// ---------------- LayerNorm; fp32 in, bf16(+fp32) out
__global__ __launch_bounds__(256) void ln_kernel(const float* __restrict__ x,
                                                 const float* __restrict__ alpha,
                                                 const float* __restrict__ beta,
                                                 u16* __restrict__ outb,
                                                 float* __restrict__ outf) {
  const int D = 1024;
  const int row = blockIdx.x;
  const int tid = threadIdx.x;
  const float4 u = *(const float4*)(x + (size_t)row * D + tid * 4);
  float s1 = u.x + u.y + u.z + u.w;
  float s2 = u.x * u.x + u.y * u.y + u.z * u.z + u.w * u.w;
#pragma unroll
  for (int off = 32; off >= 1; off >>= 1) {
    s1 += __shfl_xor(s1, off, 64);
    s2 += __shfl_xor(s2, off, 64);
  }
  __shared__ float ws1[4], ws2[4];
  if ((tid & 63) == 0) { ws1[tid >> 6] = s1; ws2[tid >> 6] = s2; }
  __syncthreads();
  s1 = ws1[0] + ws1[1] + ws1[2] + ws1[3];
  s2 = ws2[0] + ws2[1] + ws2[2] + ws2[3];
  const float mean = s1 * (1.0f / 1024.0f);
  const float var = fmaxf((s2 - 1024.0f * mean * mean) * (1.0f / 1023.0f), 0.0f);
  const float inv = 1.0f / (sqrtf(var) + 1e-6f);
  const float4 a = *(const float4*)(alpha + tid * 4);
  const float4 b = *(const float4*)(beta + tid * 4);
  const float o0 = a.x * (u.x - mean) * inv + b.x;
  const float o1 = a.y * (u.y - mean) * inv + b.y;
  const float o2 = a.z * (u.z - mean) * inv + b.z;
  const float o3 = a.w * (u.w - mean) * inv + b.w;
  ushort4 ob; ob.x = f2b(o0); ob.y = f2b(o1); ob.z = f2b(o2); ob.w = f2b(o3);
  *(ushort4*)(outb + (size_t)row * D + tid * 4) = ob;
  if (outf) {
    float4 of; of.x = o0; of.y = o1; of.z = o2; of.w = o3;
    *(float4*)(outf + (size_t)row * D + tid * 4) = of;
  }
}

// ---------------- Templated MFMA GEMM: C = A(MxK) @ Bt(NxK)^T + bias [+resid] [relu]
// TMxTN tile, 4 waves, BK=32, global_load_lds width=16.
// TM=128: waves 2x2 of 64x64. TM=64: waves 1x4 of 64x(TN/4).
template<int TM, int TN>
__global__ __launch_bounds__(256) void gemm_t(
    const u16* __restrict__ A, const u16* __restrict__ A2,
    const u16* __restrict__ Bt, const float* __restrict__ bias,
    const float* __restrict__ resid, float* __restrict__ Cf, u16* __restrict__ Cb,
    int M, int N, int K, int K1, int relu) {
  __shared__ __align__(16) u16 As[TM * 32];
  __shared__ __align__(16) u16 Bs[TN * 32];
  const int tid = threadIdx.x;
  const int bn = blockIdx.x * TN;
  const int bm = blockIdx.y * TM;
  const int wv = tid >> 6, lane = tid & 63, quad = lane >> 4, l16 = lane & 15;
  constexpr int WN = (TM == 128) ? 64 : TN / 4;
  constexpr int AM = 4, AN = WN / 16;
  const int wm = (TM == 128) ? (wv >> 1) * 64 : 0;
  const int wn = (TM == 128) ? (wv & 1) * 64 : wv * WN;
  const int r0 = tid >> 2;
  const int cc = (tid & 3) * 8;
  f32x4 acc[AM][AN];
#pragma unroll
  for (int i = 0; i < AM; ++i)
#pragma unroll
    for (int j = 0; j < AN; ++j) acc[i][j] = (f32x4){0.f, 0.f, 0.f, 0.f};

  for (int k0 = 0; k0 < K; k0 += 32) {
    const u16* aS; int lda, kk;
    if (A2 != nullptr && k0 >= K1) { aS = A2; lda = K - K1; kk = k0 - K1; }
    else { aS = A; lda = (A2 != nullptr) ? K1 : K; kk = k0; }
#pragma unroll
    for (int i = 0; i < TM / 64; ++i)
      gld16(&As[i * 2048 + tid * 8], aS + (size_t)(bm + i * 64 + r0) * lda + kk + cc);
#pragma unroll
    for (int i = 0; i < TN / 64; ++i)
      gld16(&Bs[i * 2048 + tid * 8], Bt + (size_t)(bn + i * 64 + r0) * K + k0 + cc);
    __syncthreads();
    short8 af[AM], bf[AN];
#pragma unroll
    for (int mi = 0; mi < AM; ++mi)
      af[mi] = *(const short8*)&As[(wm + mi * 16 + l16) * 32 + quad * 8];
#pragma unroll
    for (int ni = 0; ni < AN; ++ni)
      bf[ni] = *(const short8*)&Bs[(wn + ni * 16 + l16) * 32 + quad * 8];
#pragma unroll
    for (int mi = 0; mi < AM; ++mi)
#pragma unroll
      for (int ni = 0; ni < AN; ++ni)
        acc[mi][ni] = mfma16(af[mi], bf[ni], acc[mi][ni]);
    __syncthreads();
  }

#pragma unroll
  for (int ni = 0; ni < AN; ++ni) {
    const int col = bn + wn + ni * 16 + l16;
    const float bb = bias ? bias[col] : 0.0f;
#pragma unroll
    for (int mi = 0; mi < AM; ++mi) {
#pragma unroll
      for (int r = 0; r < 4; ++r) {
        const int row = bm + wm + mi * 16 + quad * 4 + r;
        const size_t off = (size_t)row * N + col;
        float v = acc[mi][ni][r] + bb;
        if (resid) v += resid[off];
        if (relu) v = fmaxf(v, 0.0f);
        if (Cf) Cf[off] = v;
        if (Cb) Cb[off] = f2b(v);
      }
    }
  }
}

// ---------------- Flash attention, transposed orientation, single-barrier pipeline.
// 64-key double-buffered tiles; K staged via swizzled global_load_lds; V prefetched
// to regs, scattered post-compute. Fixed-reference softmax (clamp 60).
// Block = (b, h, 128 q rows); wave = 32 q rows.
__global__ __launch_bounds__(256) void attn_kernel(
    const u16* __restrict__ Q, const u16* __restrict__ Kb,
    const u16* __restrict__ Vb, u16* __restrict__ O, int ldq) {
  const int S = 2048, NT = 32;
  __shared__ __align__(16) u16 Ks[2][64][64];   // swizzled: chunk c stored at c^(key&7)
  __shared__ __align__(16) u16 Vt[2][64][72];   // [dh][key], +8 pad
  __shared__ __align__(16) u16 Pb[4][32][40];   // per-wave P^T: [qrow][key32]
  const int tid = threadIdx.x;
  const int qt = blockIdx.x & 15;
  const int bh = blockIdx.x >> 4;
  const int b = bh >> 4, h = bh & 15;
  const int wv = tid >> 6, lane = tid & 63, quad = lane >> 4, l16 = lane & 15;
  const size_t brow = (size_t)b * S;
  const size_t hoff = (size_t)h * 64;
  const int q0 = qt * 128 + wv * 32;

  // Q B-frags [ni][ks], scaled by 0.125
  short8 qf[2][2];
#pragma unroll
  for (int ni = 0; ni < 2; ++ni)
#pragma unroll
    for (int ks = 0; ks < 2; ++ks) {
      int4 t = *(const int4*)(Q + (brow + q0 + ni * 16 + l16) * ldq + hoff + ks * 32 + quad * 8);
      const u16* p = (const u16*)&t;
      short8 f;
#pragma unroll
      for (int j = 0; j < 8; ++j) f[j] = (short)f2b(b2f(p[j]) * 0.125f);
      qf[ni][ks] = f;
    }

  f32x4 oacc[4][2];
#pragma unroll
  for (int mi = 0; mi < 4; ++mi)
#pragma unroll
    for (int ni = 0; ni < 2; ++ni) oacc[mi][ni] = (f32x4){0.f, 0.f, 0.f, 0.f};
  float lsum[2] = {0.0f, 0.0f};
  const f32x4 z4 = {0.f, 0.f, 0.f, 0.f};

  // ---- prologue: stage tile 0 into buffer 0
#pragma unroll
  for (int it = 0; it < 2; ++it) {
    const int s = it * 256 + tid;
    const int key = s >> 3, c = (s & 7) ^ (key & 7);
    gld16(&Ks[0][0][0] + (size_t)s * 8, Kb + (brow + key) * ldq + hoff + c * 8);
  }
#pragma unroll
  for (int it = 0; it < 2; ++it) {
    const int idx = it * 256 + tid;
    const int key = idx >> 3, c0 = (idx & 7) * 8;
    int4 vv = *(const int4*)(Vb + (brow + key) * ldq + hoff + c0);
    const u16* vp = (const u16*)&vv;
    const int rot = idx & 7;
#pragma unroll
    for (int j0 = 0; j0 < 8; ++j0) {
      const int j = (j0 + rot) & 7;
      Vt[0][c0 + j][key] = vp[j];
    }
  }
  __syncthreads();

  for (int t = 0; t < NT; ++t) {
    const int p = t & 1, np = p ^ 1;
    int4 va[2];
    if (t + 1 < NT) {
      const int kbn = (t + 1) * 64;
#pragma unroll
      for (int it = 0; it < 2; ++it) {
        const int s = it * 256 + tid;
        const int key = s >> 3, c = (s & 7) ^ (key & 7);
        gld16(&Ks[np][0][0] + (size_t)s * 8, Kb + (brow + kbn + key) * ldq + hoff + c * 8);
      }
#pragma unroll
      for (int it = 0; it < 2; ++it) {
        const int idx = it * 256 + tid;
        const int key = idx >> 3, c0 = (idx & 7) * 8;
        va[it] = *(const int4*)(Vb + (brow + kbn + key) * ldq + hoff + c0);
      }
    }

    // ---- compute tile t from buffer p
    const u16* ksb = &Ks[p][0][0];
#pragma unroll
    for (int kk = 0; kk < 2; ++kk) {
#pragma unroll
      for (int half = 0; half < 2; ++half) {
        const int m = (kk * 2 + half) * 16 + l16;
        short8 af0 = *(const short8*)(ksb + m * 64 + ((quad ^ (m & 7)) * 8));
        short8 af1 = *(const short8*)(ksb + m * 64 + (((4 + quad) ^ (m & 7)) * 8));
#pragma unroll
        for (int ni = 0; ni < 2; ++ni) {
          f32x4 s = z4;
          s = mfma16(af0, qf[ni][0], s);
          s = mfma16(af1, qf[ni][1], s);
          const float e0 = __expf(fminf(s[0], 60.0f));
          const float e1 = __expf(fminf(s[1], 60.0f));
          const float e2 = __expf(fminf(s[2], 60.0f));
          const float e3 = __expf(fminf(s[3], 60.0f));
          lsum[ni] += (e0 + e1) + (e2 + e3);
          uint2 pk;
          pk.x = pk2(e0, e1);
          pk.y = pk2(e2, e3);
          *(uint2*)&Pb[wv][ni * 16 + l16][half * 16 + quad * 4] = pk;
        }
      }
      short8 pf[2];
#pragma unroll
      for (int ni = 0; ni < 2; ++ni)
        pf[ni] = *(const short8*)&Pb[wv][ni * 16 + l16][quad * 8];
#pragma unroll
      for (int mi2 = 0; mi2 < 4; ++mi2) {
        short8 vf = *(const short8*)&Vt[p][mi2 * 16 + l16][kk * 32 + quad * 8];
#pragma unroll
        for (int ni = 0; ni < 2; ++ni)
          oacc[mi2][ni] = mfma16(vf, pf[ni], oacc[mi2][ni]);
      }
    }

    if (t + 1 < NT) {
#pragma unroll
      for (int it = 0; it < 2; ++it) {
        const int idx = it * 256 + tid;
        const int key = idx >> 3, c0 = (idx & 7) * 8;
        const u16* vp = (const u16*)&va[it];
        const int rot = idx & 7;
#pragma unroll
        for (int j0 = 0; j0 < 8; ++j0) {
          const int j = (j0 + rot) & 7;
          Vt[np][c0 + j][key] = vp[j];
        }
      }
      __syncthreads();
    }
  }

#pragma unroll
  for (int ni = 0; ni < 2; ++ni) {
    lsum[ni] += __shfl_xor(lsum[ni], 16, 64);
    lsum[ni] += __shfl_xor(lsum[ni], 32, 64);
  }
#pragma unroll
  for (int ni = 0; ni < 2; ++ni) {
    const float rl = 1.0f / lsum[ni];
    const size_t ob = (brow + q0 + ni * 16 + l16) * 1024 + hoff;
#pragma unroll
    for (int mi2 = 0; mi2 < 4; ++mi2) {
      uint2 ov;
      ov.x = pk2(oacc[mi2][ni][0] * rl, oacc[mi2][ni][1] * rl);
      ov.y = pk2(oacc[mi2][ni][2] * rl, oacc[mi2][ni][3] * rl);
      *(uint2*)(O + ob + mi2 * 16 + quad * 4) = ov;
    }
  }
}

extern "C" void kernel_launch(void* const* d_in, const int* in_sizes, int n_in,
                              void* d_out, int out_size, void* d_ws, size_t ws_size,
                              hipStream_t stream) {
  const int M = 8192, D = 1024, P = 256, DFF = 512;

  const float* feature_x = (const float*)d_in[0];
  const float* param_x   = (const float*)d_in[1];
  const float* Wq = (const float*)d_in[2];  const float* bq = (const float*)d_in[3];
  const float* Wk = (const float*)d_in[4];  const float* bk = (const float*)d_in[5];
  const float* Wv = (const float*)d_in[6];  const float* bv = (const float*)d_in[7];
  const float* Wo = (const float*)d_in[8];  const float* bo = (const float*)d_in[9];
  const float* alpha1 = (const float*)d_in[10]; const float* beta1 = (const float*)d_in[11];
  const float* alpha2 = (const float*)d_in[12]; const float* beta2 = (const float*)d_in[13];
  const float* W1 = (const float*)d_in[14]; const float* b1 = (const float*)d_in[15];
  const float* W2 = (const float*)d_in[16]; const float* b2 = (const float*)d_in[17];
  const float* Wp = (const float*)d_in[18]; const float* bp = (const float*)d_in[19];

  void* sym = nullptr;
  hipGetSymbolAddress(&sym, HIP_SYMBOL(g_ws));
  u16* s = (u16*)sym;

  u16* xn_b   = s + (size_t)MELEM * 0;
  float* xn_f = (float*)(s + (size_t)MELEM * 1);   // slots 1-2
  u16* qkv_b  = s + (size_t)MELEM * 3;             // slots 3-5 (M x 3072)
  u16* ctx    = s + (size_t)MELEM * 6;
  float* x1_f = (float*)(s + (size_t)MELEM * 7);   // slots 7-8
  u16* x2_b   = s + (size_t)MELEM * 9;
  u16* h1_b   = s + (size_t)MELEM * 10;            // M x 512
  u16* xcp_b  = s + (size_t)MELEM * 11;
  u16* wreg   = s + (size_t)MELEM * 12;
  u16* px_b   = wreg;                              // M x 256
  u16* Wqkvt  = px_b + 2097152;                    // 3072 x 1024
  u16* Wot    = Wqkvt + 3145728;                   // 1024 x 1024
  u16* W1t    = Wot + 1048576;                     // 512 x 1024
  u16* W2t    = W1t + 524288;                      // 1024 x 512
  u16* Wpt    = W2t + 524288;                      // 256 x 1280
  float* bqkv = (float*)(Wpt + 327680);            // 3072 fp32

  float* xout_f = (float*)d_out;
  float* pout_f = xout_f + (size_t)M * D;

  dim3 blk(256);
  // weight prep
  transpose_kernel<<<dim3(32, 32), blk, 0, stream>>>(Wq, Wqkvt, D, D);
  transpose_kernel<<<dim3(32, 32), blk, 0, stream>>>(Wk, Wqkvt + 1024 * 1024, D, D);
  transpose_kernel<<<dim3(32, 32), blk, 0, stream>>>(Wv, Wqkvt + 2048 * 1024, D, D);
  transpose_kernel<<<dim3(32, 32), blk, 0, stream>>>(Wo, Wot, D, D);
  transpose_kernel<<<dim3(16, 32), blk, 0, stream>>>(W1, W1t, D, DFF);
  transpose_kernel<<<dim3(32, 16), blk, 0, stream>>>(W2, W2t, DFF, D);
  transpose_kernel<<<dim3(8, 40), blk, 0, stream>>>(Wp, Wpt, D + P, P);
  concat3_kernel<<<12, blk, 0, stream>>>(bq, bk, bv, bqkv);
  convert_kernel<<<(M * P + 255) / 256, blk, 0, stream>>>(param_x, px_b, M * P);

  // pipeline
  ln_kernel<<<M, blk, 0, stream>>>(feature_x, alpha1, beta1, xn_b, xn_f);
  gemm_t<128, 128><<<dim3(24, 64), blk, 0, stream>>>(xn_b, nullptr, Wqkvt, bqkv, nullptr,
                                                     nullptr, qkv_b, M, 3072, D, D, 0);
  attn_kernel<<<1024, blk, 0, stream>>>(qkv_b, qkv_b + 1024, qkv_b + 2048, ctx, 3072);
  gemm_t<128, 128><<<dim3(8, 64), blk, 0, stream>>>(ctx, nullptr, Wot, bo, xn_f,
                                                    x1_f, nullptr, M, D, D, D, 0);
  ln_kernel<<<M, blk, 0, stream>>>(x1_f, alpha2, beta2, x2_b, nullptr);
  gemm_t<64, 128><<<dim3(4, 128), blk, 0, stream>>>(x2_b, nullptr, W1t, b1, nullptr,
                                                    nullptr, h1_b, M, DFF, D, D, 1);
  gemm_t<128, 128><<<dim3(8, 64), blk, 0, stream>>>(h1_b, nullptr, W2t, b2, x1_f,
                                                    xout_f, xcp_b, M, D, DFF, DFF, 0);
  gemm_t<64, 64><<<dim3(4, 128), blk, 0, stream>>>(xcp_b, px_b, Wpt, bp, nullptr,
                                                   pout_f, nullptr, M, P, D + P, D, 0);
}